// Round 1
// baseline (558.242 us; speedup 1.0000x reference)
//
#include <hip/hip_runtime.h>
#include <math.h>

#define BATCH   16384
#define EMB_D   128
#define NEG_K   5
#define WAVES_PER_BLOCK 16   // 1024 threads

__device__ __forceinline__ float log_sigmoid_f(float x) {
    // stable: min(x,0) - log1p(exp(-|x|))
    return fminf(x, 0.0f) - log1pf(expf(-fabsf(x)));
}

__global__ __launch_bounds__(WAVES_PER_BLOCK * 64)
void skipgram_loss_kernel(const float* __restrict__ emb,
                          const int*   __restrict__ centers,
                          const int*   __restrict__ contexts,
                          const int*   __restrict__ negs,
                          float*       __restrict__ out) {
    const int wid  = threadIdx.x >> 6;   // wave id in block: 0..15
    const int lane = threadIdx.x & 63;   // 0..63
    const int row  = blockIdx.x * WAVES_PER_BLOCK + wid;

    float loss = 0.0f;

    if (row < BATCH) {
        // wave-uniform index loads (broadcast via cache)
        const int c_idx = centers[row];
        const int v_idx = contexts[row];
        int n_idx[NEG_K];
        #pragma unroll
        for (int k = 0; k < NEG_K; ++k) n_idx[k] = negs[row * NEG_K + k];

        // each embedding row = 64 float2; lane l takes pair l  (512B coalesced/wave)
        const float2* __restrict__ embv = (const float2*)emb;

        // issue all 7 gathers before any use (7 outstanding loads/lane)
        float2 u  = embv[(size_t)c_idx * (EMB_D / 2) + lane];
        float2 v  = embv[(size_t)v_idx * (EMB_D / 2) + lane];
        float2 nv[NEG_K];
        #pragma unroll
        for (int k = 0; k < NEG_K; ++k)
            nv[k] = embv[(size_t)n_idx[k] * (EMB_D / 2) + lane];

        float pos = u.x * v.x + u.y * v.y;
        float neg = 0.0f;
        #pragma unroll
        for (int k = 0; k < NEG_K; ++k)
            neg += u.x * nv[k].x + u.y * nv[k].y;

        // 64-lane butterfly reduction
        #pragma unroll
        for (int off = 32; off > 0; off >>= 1) {
            pos += __shfl_xor(pos, off, 64);
            neg += __shfl_xor(neg, off, 64);
        }

        if (lane == 0)
            loss = log_sigmoid_f(pos) + log_sigmoid_f(-neg);
    }

    // block reduce: 16 wave scalars -> 1 atomic per block
    __shared__ float s_wave[WAVES_PER_BLOCK];
    if (lane == 0) s_wave[wid] = loss;
    __syncthreads();

    if (threadIdx.x == 0) {
        float t = 0.0f;
        #pragma unroll
        for (int i = 0; i < WAVES_PER_BLOCK; ++i) t += s_wave[i];
        atomicAdd(out, -t);   // reference returns -sum(loss)
    }
}

extern "C" void kernel_launch(void* const* d_in, const int* in_sizes, int n_in,
                              void* d_out, int out_size, void* d_ws, size_t ws_size,
                              hipStream_t stream) {
    const float* emb      = (const float*)d_in[0];
    const int*   centers  = (const int*)d_in[1];
    const int*   contexts = (const int*)d_in[2];
    const int*   negs     = (const int*)d_in[3];
    float*       out      = (float*)d_out;

    // d_out is poisoned (0xAA) before every timed replay -> zero it (capture-safe)
    hipMemsetAsync(out, 0, sizeof(float), stream);

    const int blocks = BATCH / WAVES_PER_BLOCK;   // 1024
    skipgram_loss_kernel<<<blocks, WAVES_PER_BLOCK * 64, 0, stream>>>(
        emb, centers, contexts, negs, out);
}